// Round 11
// baseline (418.496 us; speedup 1.0000x reference)
//
#include <hip/hip_runtime.h>
#include <math.h>

#define B_ 16
#define N_ 512
#define D_ 32
#define E_ 8176
#define SLEFT_ 16384
#define FSS_ 601
#define BN_ (B_*N_)            // 8192
#define BE_ (B_*E_)            // 130816
#define NSROW_ (SLEFT_ + 2*E_) // 32736
#define OUT_R_ (B_*FSS_)       // 9616
#define HLD_ 768               // combined width: reward 0..639, next 640..767

typedef __attribute__((ext_vector_type(8))) short short8;
typedef __attribute__((ext_vector_type(4))) float f32x4;

typedef __attribute__((address_space(3))) uint lds_uint;
typedef __attribute__((address_space(1))) const uint g_uint;

__device__ __forceinline__ void gl_lds16(const ushort* gp, ushort* lp) {
  __builtin_amdgcn_global_load_lds((g_uint*)gp, (lds_uint*)lp, 16, 0, 0);
}

__device__ __forceinline__ ushort f2b(float f) {
  uint u = __builtin_bit_cast(uint, f);
  u += 0x7FFFu + ((u >> 16) & 1u);
  return (ushort)(u >> 16);
}
__device__ __forceinline__ float b2f(ushort h) {
  return __builtin_bit_cast(float, ((uint)h) << 16);
}

// ---------------- index / CSR build ----------------

__global__ __launch_bounds__(256) void k_indices(const float* __restrict__ ns,
                                                 int* __restrict__ src_i,
                                                 int* __restrict__ dst_i,
                                                 int* __restrict__ cnt) {
  int idx = blockIdx.x*256 + threadIdx.x;
  if (idx >= BE_) return;
  int b = idx / E_;
  int j = idx - b*E_;
  const float* row = ns + (size_t)b*NSROW_;
  int s = (int)row[SLEFT_ + j];
  int r = (int)row[SLEFT_ + E_ + j];
  src_i[idx] = b*N_ + s;
  int dst = b*N_ + r;
  dst_i[idx] = dst;
  atomicAdd(&cnt[dst], 1);
}

__global__ __launch_bounds__(1024) void k_scan(const int* __restrict__ cnt,
                                               int* __restrict__ rowptr) {
  __shared__ int part[1024];
  int t = threadIdx.x;
  int base = t*8;
  int loc[8]; int s = 0;
  #pragma unroll
  for (int i=0;i<8;i++){ loc[i]=cnt[base+i]; s+=loc[i]; }
  part[t]=s; __syncthreads();
  for (int off=1; off<1024; off<<=1) {
    int v = (t>=off)?part[t-off]:0;
    __syncthreads();
    part[t]+=v;
    __syncthreads();
  }
  int ex = (t==0)?0:part[t-1];
  #pragma unroll
  for (int i=0;i<8;i++){ rowptr[base+i]=ex; ex+=loc[i]; }
  if (t==1023) rowptr[BN_]=ex;
}

__global__ __launch_bounds__(256) void k_scatter(const int* __restrict__ src_i,
                                                 const int* __restrict__ dst_i,
                                                 const int* __restrict__ rowptr,
                                                 int* __restrict__ fill,
                                                 int* __restrict__ csr_src) {
  int idx = blockIdx.x*256+threadIdx.x;
  if (idx>=BE_) return;
  int dst = dst_i[idx];
  int pos = rowptr[dst] + atomicAdd(&fill[dst],1);
  csr_src[pos] = src_i[idx];
}

// ---------------- sa (bf16, padded to K=64) ----------------

__global__ __launch_bounds__(256) void k_sa(const float* __restrict__ ns,
                                            const int* __restrict__ a,
                                            ushort* __restrict__ sa) {
  int idx = blockIdx.x*256+threadIdx.x;
  if (idx >= BN_*64) return;
  int v = idx >> 6, c = idx & 63;
  int b = v >> 9, n = v & 511;
  float val = 0.f;
  if (c < 32)       val = ns[(size_t)b*NSROW_ + n*32 + c];
  else if (c == 32) val = (a[b]==n) ? 1.f : 0.f;
  sa[idx] = f2b(val);
}

// ---------------- LDS-tiled block-diagonal weight transpose ---------------

struct WtP { const float* Wr[4]; const float* Wn[4]; ushort* T[4]; };

__global__ __launch_bounds__(256) void k_wt_tr(WtP p) {
  int t = blockIdx.x;
  int s, base, KP, DINR, DINN, DOUTN, KOFF;
  if (t < 48)        { s=0; base=0;    KP=64;  DINR=33;  DINN=33;  DOUTN=128; KOFF=0;   }
  else if (t < 600)  { s=1; base=48;   KP=736; DINR=601; DINN=128; DOUTN=64;  KOFF=608; }
  else if (t < 1104) { s=2; base=600;  KP=672; DINR=601; DINN=64;  DOUTN=64;  KOFF=608; }
  else               { s=3; base=1104; KP=672; DINR=601; DINN=64;  DOUTN=32;  KOFF=608; }
  int ti = t - base;
  int kt = ti / 24, nt = ti - kt*24;
  int k0 = kt*32, n0 = nt*32;
  __shared__ float tile[32][33];
  int tid = threadIdx.x;
  int cc = tid & 31, rr = tid >> 5;
  #pragma unroll
  for (int it=0; it<4; it++) {
    int k = k0 + it*8 + rr;
    int n = n0 + cc;
    float v = 0.f;
    if (n < 640) { if (n < 601 && k < DINR) v = p.Wr[s][(size_t)k*601 + n]; }
    else { int nn = n-640, kk = k-KOFF;
           if (nn < DOUTN && kk >= 0 && kk < DINN) v = p.Wn[s][(size_t)kk*DOUTN + nn]; }
    tile[it*8+rr][cc] = v;
  }
  __syncthreads();
  #pragma unroll
  for (int it=0; it<4; it++) {
    int n = n0 + it*8 + rr;
    int k = k0 + cc;
    p.T[s][(size_t)n*KP + k] = f2b(tile[cc][it*8+rr]);
  }
}

// ---------------- weight GEMM transposed: ht[768][8192] = Wt x X^T --------
// Epilogue: per-head attention dots routed by row tile (640 = 10*64 clean
// boundary): rowBase<640 -> es_r/ed_r, else es_n/ed_n (atomicAdd, pre-zeroed).

__global__ __launch_bounds__(256) void k_gemmT(const ushort* __restrict__ Wt,
                                               const ushort* __restrict__ X,
                                               ushort* __restrict__ ht,
                                               float* __restrict__ esed, // [4][BN]
                                               const float* __restrict__ asr,
                                               const float* __restrict__ adr,
                                               const float* __restrict__ asn,
                                               const float* __restrict__ adn,
                                               int Kpad, int dn) {
  __shared__ ushort Asm[64*32];
  __shared__ ushort Bsm[128*32];
  int tid = threadIdx.x;
  int rowBase = blockIdx.y * 64;     // over 768 output-feature rows
  int colBase = blockIdx.x * 128;    // over 8192 nodes
  int wave = tid >> 6, lane = tid & 63;
  int wr = (wave >> 1) * 32, wc = (wave & 1) * 64;
  int lm = lane & 15, lk = (lane >> 4) * 8;

  f32x4 acc[2][4];
  #pragma unroll
  for (int i=0;i<2;i++)
    #pragma unroll
    for (int j=0;j<4;j++) acc[i][j] = (f32x4){0.f,0.f,0.f,0.f};

  int t0 = tid, t1 = tid + 256;
  const ushort* Ag0 = Wt + (size_t)(rowBase + (t0>>2))*Kpad + (t0&3)*8;
  const ushort* Bg0 = X  + (size_t)(colBase + (t0>>2))*Kpad + (t0&3)*8;
  const ushort* Bg1 = X  + (size_t)(colBase + (t1>>2))*Kpad + (t1&3)*8;
  ushort* Al0 = &Asm[t0*8];
  ushort* Bl0 = &Bsm[t0*8];
  ushort* Bl1 = &Bsm[t1*8];

  for (int k0 = 0; k0 < Kpad; k0 += 32) {
    gl_lds16(Ag0 + k0, Al0);
    gl_lds16(Bg0 + k0, Bl0);
    gl_lds16(Bg1 + k0, Bl1);
    __syncthreads();
    short8 af[2], bfr[4];
    #pragma unroll
    for (int i=0;i<2;i++) af[i]  = *(short8*)&Asm[(wr + i*16 + lm)*32 + lk];
    #pragma unroll
    for (int j=0;j<4;j++) bfr[j] = *(short8*)&Bsm[(wc + j*16 + lm)*32 + lk];
    #pragma unroll
    for (int i=0;i<2;i++)
      #pragma unroll
      for (int j=0;j<4;j++)
        acc[i][j] = __builtin_amdgcn_mfma_f32_16x16x32_bf16(af[i], bfr[j], acc[i][j], 0,0,0);
    __syncthreads();
  }

  int cr = lane >> 4;
  float asv[2][4], adv[2][4];
  #pragma unroll
  for (int i=0;i<2;i++)
    #pragma unroll
    for (int g=0; g<4; g++) {
      int r = rowBase + wr + i*16 + cr*4 + g;
      float s = 0.f, d = 0.f;
      if (r < 601)                        { s = asr[r];     d = adr[r]; }
      else if (r >= 640 && r - 640 < dn)  { s = asn[r-640]; d = adn[r-640]; }
      asv[i][g] = s; adv[i][g] = d;
    }

  #pragma unroll
  for (int i=0;i<2;i++) {
    #pragma unroll
    for (int j=0;j<4;j++) {
      int col = colBase + wc + j*16 + lm;
      #pragma unroll
      for (int g=0; g<4; g++) {
        int r = rowBase + wr + i*16 + cr*4 + g;
        ht[(size_t)r*BN_ + col] = f2b(acc[i][j][g]);
      }
    }
  }
  // route: this block's rows are entirely one head
  float* es = (rowBase < 640) ? esed          : esed + 2*BN_;
  float* ed = (rowBase < 640) ? esed + BN_    : esed + 3*BN_;
  #pragma unroll
  for (int j=0;j<4;j++) {
    float se = 0.f, sd = 0.f;
    #pragma unroll
    for (int i=0;i<2;i++)
      #pragma unroll
      for (int g=0; g<4; g++) { se += acc[i][j][g]*asv[i][g]; sd += acc[i][j][g]*adv[i][g]; }
    se += __shfl_xor(se, 16, 64); se += __shfl_xor(se, 32, 64);
    sd += __shfl_xor(sd, 16, 64); sd += __shfl_xor(sd, 32, 64);
    if (cr == 0) {
      int v = colBase + wc + j*16 + lm;
      atomicAdd(&es[v], se);
      atomicAdd(&ed[v], sd);
    }
  }
}

// ---------------- build dense softmax rows for BOTH heads -----------------
// Pm[v*1024 + 0..511] = reward-head alpha row; [+512..1023] = next-head.
// One wave per node; lane i owns cols [8i,8i+8). Exact for duplicate edges.

__global__ __launch_bounds__(256) void k_pbuild(const float* __restrict__ esed,
                                                const int* __restrict__ rowptr,
                                                const int* __restrict__ csr,
                                                ushort* __restrict__ Pm) {
  const float* es_r = esed;
  const float* ed_r = esed + BN_;
  const float* es_n = esed + 2*BN_;
  const float* ed_n = esed + 3*BN_;
  int wid = threadIdx.x>>6, lane = threadIdx.x&63;
  int v = blockIdx.x*4 + wid;
  int s0 = rowptr[v], e0 = rowptr[v+1];
  float edr = ed_r[v], edn = ed_n[v];

  float mr = -__builtin_inff(), mn = -__builtin_inff();
  for (int c0 = s0; c0 < e0; c0 += 64) {
    int j = c0 + lane;
    float er = -__builtin_inff(), en = -__builtin_inff();
    if (j < e0) {
      int u = csr[j];
      er = es_r[u] + edr; er = er > 0.f ? er : 0.2f*er;
      en = es_n[u] + edn; en = en > 0.f ? en : 0.2f*en;
    }
    mr = fmaxf(mr, er); mn = fmaxf(mn, en);
  }
  #pragma unroll
  for (int o=32;o;o>>=1) { mr = fmaxf(mr, __shfl_xor(mr,o,64)); mn = fmaxf(mn, __shfl_xor(mn,o,64)); }

  float accr[8], accn[8];
  #pragma unroll
  for (int q=0;q<8;q++){ accr[q]=0.f; accn[q]=0.f; }
  float denr = 0.f, denn = 0.f;
  for (int c0 = s0; c0 < e0; c0 += 64) {
    int j = c0 + lane;
    int u = 0; float pwr = 0.f, pwn = 0.f;
    if (j < e0) {
      u = csr[j];
      float er = es_r[u] + edr; er = er > 0.f ? er : 0.2f*er;
      float en = es_n[u] + edn; en = en > 0.f ? en : 0.2f*en;
      pwr = __expf(er - mr);
      pwn = __expf(en - mn);
    }
    denr += pwr; denn += pwn;
    int cl = e0 - c0; if (cl > 64) cl = 64;
    for (int t = 0; t < cl; ++t) {
      float pr = __shfl(pwr, t, 64);
      float pn = __shfl(pwn, t, 64);
      int   uu = __shfl(u,   t, 64);
      int rel = (uu & 511) - (lane<<3);
      if (rel >= 0 && rel < 8) {
        #pragma unroll
        for (int q=0;q<8;q++) if (rel==q) { accr[q] += pr; accn[q] += pn; }
      }
    }
  }
  #pragma unroll
  for (int o=32;o;o>>=1) { denr += __shfl_xor(denr,o,64); denn += __shfl_xor(denn,o,64); }
  float scr = 1.f/(denr + 1e-16f);
  float scn = 1.f/(denn + 1e-16f);
  short8 ovr, ovn;
  #pragma unroll
  for (int q=0;q<8;q++) { ovr[q] = (short)f2b(accr[q]*scr); ovn[q] = (short)f2b(accn[q]*scn); }
  *(short8*)&Pm[(size_t)v*1024 + lane*8]       = ovr;
  *(short8*)&Pm[(size_t)v*1024 + 512 + lane*8] = ovn;
}

// ---------------- aggregation GEMM: g[v][768] = P_head[v][:] x H + bias ---
// Column tile bx==5 (cols 640..767) is the next head -> use P_n (offset 512).

__global__ __launch_bounds__(256) void k_pgemm(const ushort* __restrict__ Pm,
                                               const ushort* __restrict__ ht,
                                               ushort* __restrict__ g,
                                               const float* __restrict__ bias_r,
                                               const float* __restrict__ bias_n,
                                               int dn) {
  __shared__ ushort Asm[64*32];
  __shared__ ushort Bsm[128*32];
  int bid = blockIdx.x;
  int xcd = bid & 7, slot = bid >> 3;
  int graph = xcd + 8*(slot/48);
  int idx = slot % 48;
  int bx = idx % 6, rt = idx / 6;
  int rowBase = graph*512 + rt*64;
  int colBase = bx*128;
  int headoff = (bx == 5) ? 512 : 0;
  int tid = threadIdx.x;
  int wave = tid >> 6, lane = tid & 63;
  int wr = (wave >> 1) * 32, wc = (wave & 1) * 64;
  int lm = lane & 15, lk = (lane >> 4) * 8;

  f32x4 acc[2][4];
  #pragma unroll
  for (int i=0;i<2;i++)
    #pragma unroll
    for (int j=0;j<4;j++) acc[i][j] = (f32x4){0.f,0.f,0.f,0.f};

  int t0 = tid, t1 = tid + 256;
  const ushort* Ag0 = Pm + (size_t)(rowBase + (t0>>2))*1024 + headoff + (t0&3)*8;
  const ushort* Bg0 = ht + (size_t)(colBase + (t0>>2))*BN_ + graph*512 + (t0&3)*8;
  const ushort* Bg1 = ht + (size_t)(colBase + (t1>>2))*BN_ + graph*512 + (t1&3)*8;
  ushort* Al0 = &Asm[t0*8];
  ushort* Bl0 = &Bsm[t0*8];
  ushort* Bl1 = &Bsm[t1*8];

  for (int k0 = 0; k0 < 512; k0 += 32) {
    gl_lds16(Ag0 + k0, Al0);
    gl_lds16(Bg0 + k0, Bl0);
    gl_lds16(Bg1 + k0, Bl1);
    __syncthreads();
    short8 af[2], bfr[4];
    #pragma unroll
    for (int i=0;i<2;i++) af[i]  = *(short8*)&Asm[(wr + i*16 + lm)*32 + lk];
    #pragma unroll
    for (int j=0;j<4;j++) bfr[j] = *(short8*)&Bsm[(wc + j*16 + lm)*32 + lk];
    #pragma unroll
    for (int i=0;i<2;i++)
      #pragma unroll
      for (int j=0;j<4;j++)
        acc[i][j] = __builtin_amdgcn_mfma_f32_16x16x32_bf16(af[i], bfr[j], acc[i][j], 0,0,0);
    __syncthreads();
  }

  int cr = lane >> 4;
  #pragma unroll
  for (int i=0;i<2;i++) {
    #pragma unroll
    for (int j=0;j<4;j++) {
      int col = colBase + wc + j*16 + lm;
      float bv; bool valid;
      if (col < 601)                        { bv = bias_r[col];     valid = true; }
      else if (col >= 640 && col-640 < dn)  { bv = bias_n[col-640]; valid = true; }
      else                                  { bv = 0.f;             valid = false; }
      #pragma unroll
      for (int gg=0; gg<4; gg++) {
        int v = rowBase + wr + i*16 + cr*4 + gg;
        float val = valid ? acc[i][j][gg] + bv : 0.f;
        g[(size_t)v*HLD_ + col] = f2b(val);
      }
    }
  }
}

// ---------------- LN stats partials over all 768 cols ----------------

__global__ __launch_bounds__(256) void k_ln_stats(const ushort* __restrict__ g,
                                                  float* __restrict__ st) {
  int b = blockIdx.y, z = blockIdx.z; int n0 = z*64;
  int lc = threadIdx.x & 63, r0 = threadIdx.x >> 6;
  int c = blockIdx.x*64 + lc;
  float s=0.f, q=0.f;
  #pragma unroll 4
  for (int i=0;i<16;i++) {
    int n = n0 + r0*16 + i;
    float x = b2f(g[(size_t)(b*N_+n)*HLD_ + c]);
    s+=x; q+=x*x;
  }
  __shared__ float S[4][64], Q[4][64];
  S[r0][lc]=s; Q[r0][lc]=q; __syncthreads();
  if (r0==0) {
    st[((size_t)(z*2+0)*B_ + b)*HLD_ + c] = S[0][lc]+S[1][lc]+S[2][lc]+S[3][lc];
    st[((size_t)(z*2+1)*B_ + b)*HLD_ + c] = Q[0][lc]+Q[1][lc]+Q[2][lc]+Q[3][lc];
  }
}

// ---------------- LN apply + ReLU (finalize folded; col pair x 16 rows) ---

__global__ __launch_bounds__(256) void k_ln_apply(const ushort* __restrict__ g,
                                                  const float* __restrict__ st,
                                                  const float* __restrict__ scr,
                                                  const float* __restrict__ ofr,
                                                  const float* __restrict__ scn,
                                                  const float* __restrict__ ofn,
                                                  ushort* __restrict__ xb,
                                                  int dn, int Kpad) {
  int tid = threadIdx.x;
  int pp = blockIdx.x*128 + (tid & 127);
  int c0 = pp*2;
  if (c0 >= Kpad) return;
  int vbase = blockIdx.y*16;
  int b = vbase >> 9;
  float mv[2], av[2];
  #pragma unroll
  for (int q=0;q<2;q++) {
    int c = c0+q;
    int cs; bool valid; float scale, offs;
    if (c < 608) { cs = c; valid = c < 601;
                   scale = valid ? scr[c] : 0.f; offs = valid ? ofr[c] : 0.f; }
    else { int cn = c - 608; cs = 640 + cn; valid = cn < dn;
           scale = valid ? scn[cn] : 0.f; offs = valid ? ofn[cn] : 0.f; }
    float mul = 0.f, add = 0.f;
    if (valid) {
      float s=0.f, qq=0.f;
      #pragma unroll
      for (int z=0;z<8;z++) {
        s  += st[((size_t)(z*2+0)*B_ + b)*HLD_ + cs];
        qq += st[((size_t)(z*2+1)*B_ + b)*HLD_ + cs];
      }
      float mu = s*(1.f/N_);
      float var = qq*(1.f/N_) - mu*mu;
      float rs = rsqrtf(var+1e-5f);
      mul = rs*scale;
      add = offs - mu*rs*scale;
    }
    mv[q] = mul; av[q] = add;
  }
  int cs0 = (c0 < 608) ? c0 : 640 + (c0 - 608);
  for (int i = tid >> 7; i < 16; i += 2) {
    int v = vbase + i;
    uint gg = *(const uint*)&g[(size_t)v*HLD_ + cs0];
    float x0 = b2f((ushort)(gg & 0xFFFFu));
    float x1 = b2f((ushort)(gg >> 16));
    float y0 = x0*mv[0] + av[0]; y0 = y0 > 0.f ? y0 : 0.f;
    float y1 = x1*mv[1] + av[1]; y1 = y1 > 0.f ? y1 : 0.f;
    *(uint*)&xb[(size_t)v*Kpad + c0] = ((uint)f2b(y1) << 16) | f2b(y0);
  }
}

// ---------------- reward: sum over nodes (slot partials) ----------------

__global__ __launch_bounds__(256) void k_rsum(const ushort* __restrict__ g,
                                              float* __restrict__ rsp) {
  int b = blockIdx.y, z = blockIdx.z; int n0 = z*64;
  int lc = threadIdx.x & 63, r0 = threadIdx.x>>6;
  int c = blockIdx.x*64 + lc;
  float s = 0.f;
  if (c < FSS_) {
    #pragma unroll 4
    for (int i=0;i<16;i++) {
      int n = n0 + r0*16 + i;
      s += b2f(g[(size_t)(b*N_+n)*HLD_ + c]);
    }
  }
  __shared__ float S[4][64];
  S[r0][lc]=s; __syncthreads();
  if (r0==0 && c<FSS_)
    rsp[((size_t)z*B_ + b)*FSS_ + c] = S[0][lc]+S[1][lc]+S[2][lc]+S[3][lc];
}

// ---------------- final: reward finalize + ns_new assembly ----------------

__global__ __launch_bounds__(256) void k_final(const float* __restrict__ rsp,
                                               const ushort* __restrict__ g,
                                               const float* __restrict__ ns,
                                               float* __restrict__ out) {
  int idx = blockIdx.x*256+threadIdx.x;
  if (idx < OUT_R_) {
    int b = idx / FSS_, c = idx - b*FSS_;
    float s = 0.f;
    #pragma unroll
    for (int z=0;z<8;z++) s += rsp[((size_t)z*B_ + b)*FSS_ + c];
    out[idx] = s;
  } else {
    int j2 = idx - OUT_R_;
    if (j2 >= B_*NSROW_) return;
    int b = j2 / NSROW_; int j = j2 - b*NSROW_;
    float v;
    if (j < SLEFT_) {
      int n = j >> 5, c = j & 31;
      v = b2f(g[(size_t)(b*N_+n)*HLD_ + 640 + c]);
    } else {
      v = ns[(size_t)b*NSROW_ + j];
    }
    out[idx] = v;
  }
}

// ---------------- host driver ----------------

extern "C" void kernel_launch(void* const* d_in, const int* in_sizes, int n_in,
                              void* d_out, int out_size, void* d_ws, size_t ws_size,
                              hipStream_t stream) {
  const float* ns = (const float*)d_in[0];
  const int*   a  = (const int*)d_in[1];

  const float *W[4], *As[4], *Ad[4], *Bb[4], *Sc[3], *Of[3];
  const float *rW[4], *rAs[4], *rAd[4], *rBb[4], *rSc[3], *rOf[3];
  int p = 2;
  for (int i=0;i<4;i++){
    W[i]=(const float*)d_in[p++]; As[i]=(const float*)d_in[p++];
    Ad[i]=(const float*)d_in[p++]; Bb[i]=(const float*)d_in[p++];
    if (i<3){ Sc[i]=(const float*)d_in[p++]; Of[i]=(const float*)d_in[p++]; }
  }
  for (int i=0;i<4;i++){
    rW[i]=(const float*)d_in[p++]; rAs[i]=(const float*)d_in[p++];
    rAd[i]=(const float*)d_in[p++]; rBb[i]=(const float*)d_in[p++];
    if (i<3){ rSc[i]=(const float*)d_in[p++]; rOf[i]=(const float*)d_in[p++]; }
  }

  char* w = (char*)d_ws;
  auto carve = [&](size_t bytes)->void* {
    void* r = (void*)w;
    w += (bytes + 255) & ~(size_t)255;
    return r;
  };
  ushort* xb   = (ushort*)carve((size_t)BN_*736*2);
  ushort* ht   = (ushort*)carve((size_t)HLD_*BN_*2);   // transposed h
  ushort* gbuf = (ushort*)carve((size_t)BN_*HLD_*2);
  ushort* Pm   = (ushort*)carve((size_t)BN_*1024*2);   // P_r | P_n per node
  ushort* sabf = (ushort*)carve((size_t)BN_*64*2);
  float* esed  = (float*)carve((size_t)4*BN_*4);       // es_r|ed_r|es_n|ed_n
  float* stp   = (float*)carve((size_t)16*B_*HLD_*4);
  float* rsp   = (float*)carve((size_t)8*B_*FSS_*4);
  int* src_i   = (int*)carve((size_t)BE_*4);
  int* dst_i   = (int*)carve((size_t)BE_*4);
  int* cnt     = (int*)carve((size_t)2*BN_*4);         // cnt | fill
  int* fill    = cnt + BN_;
  int* rowptr  = (int*)carve((size_t)(BN_+1)*4);
  int* csr_src = (int*)carve((size_t)BE_*4);
  ushort* Wt[4];
  Wt[0] = (ushort*)carve((size_t)768*64*2);
  Wt[1] = (ushort*)carve((size_t)768*736*2);
  Wt[2] = (ushort*)carve((size_t)768*672*2);
  Wt[3] = (ushort*)carve((size_t)768*672*2);

  float* out = (float*)d_out;

  hipMemsetAsync(cnt, 0, (size_t)2*BN_*4, stream);

  k_indices<<<(BE_+255)/256, 256, 0, stream>>>(ns, src_i, dst_i, cnt);
  k_scan<<<1, 1024, 0, stream>>>(cnt, rowptr);
  k_scatter<<<(BE_+255)/256, 256, 0, stream>>>(src_i, dst_i, rowptr, fill, csr_src);
  k_sa<<<(BN_*64+255)/256, 256, 0, stream>>>(ns, a, sabf);

  WtP wtp;
  for (int i=0;i<4;i++){ wtp.Wr[i]=rW[i]; wtp.Wn[i]=W[i]; wtp.T[i]=Wt[i]; }
  k_wt_tr<<<1608, 256, 0, stream>>>(wtp);

  dim3 tg(64, 12);   // gemmT grid: 64 node-tiles x 12 feature-tiles

  const ushort* xin[4] = { sabf, xb, xb, xb };
  int Kp[4] = { 64, 736, 672, 672 };
  int dns[4] = { 128, 64, 64, 32 };

  for (int L=0; L<4; ++L) {
    hipMemsetAsync(esed, 0, (size_t)4*BN_*4, stream);
    k_gemmT<<<tg, 256, 0, stream>>>(Wt[L], xin[L], ht, esed,
                                    rAs[L], rAd[L], As[L], Ad[L], Kp[L], dns[L]);
    k_pbuild<<<BN_/4, 256, 0, stream>>>(esed, rowptr, csr_src, Pm);
    k_pgemm<<<768, 256, 0, stream>>>(Pm, ht, gbuf, rBb[L], Bb[L], dns[L]);
    if (L < 3) {
      k_ln_stats<<<dim3(12, B_, 8), 256, 0, stream>>>(gbuf, stp);
      int Kpn = (L==0) ? 736 : 672;
      k_ln_apply<<<dim3(3, BN_/16), 256, 0, stream>>>(gbuf, stp,
                  rSc[L], rOf[L], Sc[L], Of[L], xb, dns[L], Kpn);
    }
  }

  k_rsum<<<dim3(10, B_, 8), 256, 0, stream>>>(gbuf, rsp);
  k_final<<<(OUT_R_ + B_*NSROW_ + 255)/256, 256, 0, stream>>>(rsp, gbuf, ns, out);
}